// Round 1
// baseline (129.560 us; speedup 1.0000x reference)
//
#include <hip/hip_runtime.h>

#define LOG2E 1.4426950408889634f

__device__ __forceinline__ float fast_exp2(float x) {
#if __has_builtin(__builtin_amdgcn_exp2f)
  return __builtin_amdgcn_exp2f(x);
#else
  return exp2f(x);
#endif
}
__device__ __forceinline__ float fast_rcp(float x) {
#if __has_builtin(__builtin_amdgcn_rcpf)
  return __builtin_amdgcn_rcpf(x);
#else
  return 1.0f / x;
#endif
}

// ---------------------------------------------------------------------------
// Stage 1: O = relu(X @ W^T + bias).  X:(2048,512) row-major, W:(512,512)
// row-major (so both operands are K-contiguous). 64x64 tile, 4x4 per thread.
// blockIdx.z selects (A,W1,b1)->Ar vs (B,W2,b2)->Br.
// ---------------------------------------------------------------------------
__global__ __launch_bounds__(256) void gemm_relu_kernel(
    const float* __restrict__ Xa, const float* __restrict__ Wa,
    const float* __restrict__ ba, float* __restrict__ Oa,
    const float* __restrict__ Xb, const float* __restrict__ Wb,
    const float* __restrict__ bb, float* __restrict__ Ob) {
  const int K = 512, N = 512;
  const float* X = blockIdx.z ? Xb : Xa;
  const float* W = blockIdx.z ? Wb : Wa;
  const float* bias = blockIdx.z ? bb : ba;
  float* O = blockIdx.z ? Ob : Oa;

  __shared__ __align__(16) float Xs[32][68];  // [k][m], pad 68 -> 16B rows, bank spread
  __shared__ __align__(16) float Ws[32][68];  // [k][n]

  int t = threadIdx.x;
  int tm = t & 15, tn = t >> 4;
  int m0 = blockIdx.x * 64, n0 = blockIdx.y * 64;

  float acc[4][4] = {};

  for (int k0 = 0; k0 < K; k0 += 32) {
#pragma unroll
    for (int l = 0; l < 2; ++l) {
      int f = t + l * 256;          // 512 float4 slots: 64 rows x 8 quads
      int row = f >> 3;
      int kq = (f & 7) << 2;
      float4 xv = *reinterpret_cast<const float4*>(&X[(m0 + row) * K + k0 + kq]);
      Xs[kq + 0][row] = xv.x; Xs[kq + 1][row] = xv.y;
      Xs[kq + 2][row] = xv.z; Xs[kq + 3][row] = xv.w;
      float4 wv = *reinterpret_cast<const float4*>(&W[(n0 + row) * K + k0 + kq]);
      Ws[kq + 0][row] = wv.x; Ws[kq + 1][row] = wv.y;
      Ws[kq + 2][row] = wv.z; Ws[kq + 3][row] = wv.w;
    }
    __syncthreads();
#pragma unroll
    for (int kk = 0; kk < 32; ++kk) {
      float4 av = *reinterpret_cast<const float4*>(&Xs[kk][tm << 2]);
      float4 bv = *reinterpret_cast<const float4*>(&Ws[kk][tn << 2]);
      acc[0][0] = fmaf(av.x, bv.x, acc[0][0]);
      acc[0][1] = fmaf(av.x, bv.y, acc[0][1]);
      acc[0][2] = fmaf(av.x, bv.z, acc[0][2]);
      acc[0][3] = fmaf(av.x, bv.w, acc[0][3]);
      acc[1][0] = fmaf(av.y, bv.x, acc[1][0]);
      acc[1][1] = fmaf(av.y, bv.y, acc[1][1]);
      acc[1][2] = fmaf(av.y, bv.z, acc[1][2]);
      acc[1][3] = fmaf(av.y, bv.w, acc[1][3]);
      acc[2][0] = fmaf(av.z, bv.x, acc[2][0]);
      acc[2][1] = fmaf(av.z, bv.y, acc[2][1]);
      acc[2][2] = fmaf(av.z, bv.z, acc[2][2]);
      acc[2][3] = fmaf(av.z, bv.w, acc[2][3]);
      acc[3][0] = fmaf(av.w, bv.x, acc[3][0]);
      acc[3][1] = fmaf(av.w, bv.y, acc[3][1]);
      acc[3][2] = fmaf(av.w, bv.z, acc[3][2]);
      acc[3][3] = fmaf(av.w, bv.w, acc[3][3]);
    }
    __syncthreads();
  }

#pragma unroll
  for (int i = 0; i < 4; ++i) {
#pragma unroll
    for (int j = 0; j < 4; ++j) {
      int n = n0 + (tn << 2) + j;
      float v = acc[i][j] + bias[n];
      O[(m0 + (tm << 2) + i) * N + n] = v > 0.f ? v : 0.f;
    }
  }
}

// ---------------------------------------------------------------------------
// Stage 2: for each (b,h) and j-slab of 32:
//   M[i,j] = sum_c tanh(A_[i,c] * B_[j,c]) * q[c]
// emit rowpart[bh][jblk][i] = sum_{j in slab} M[i,j]
//      colsum[bh][j]        = sum_i M[i,j]      (complete: block covers all i)
// A_[b,h,i,c] = Arelu[bh*16384 + i*64 + c] (raw row-major reshape).
// Thread t owns i=t; B-slab staged in LDS with 2*log2(e) folded in.
// ---------------------------------------------------------------------------
__global__ __launch_bounds__(256) void attmap_kernel(
    const float* __restrict__ Ar, const float* __restrict__ Br,
    const float* __restrict__ q, float* __restrict__ rowpart,
    float* __restrict__ colsum) {
  int bh = blockIdx.x, jblk = blockIdx.y;
  int t = threadIdx.x;
  __shared__ __align__(16) float Bs[32][64];
  __shared__ float qs[64];
  __shared__ float cpart[4][32];
  const float SC = 2.8853900817779268f;  // 2 * log2(e)

  const float* Bbase = Br + bh * 16384 + jblk * 2048;
#pragma unroll
  for (int l = 0; l < 2; ++l) {
    int f = t + l * 256;  // 512 float4 slots: 32 rows x 16 quads
    int row = f >> 4;
    int c4 = (f & 15) << 2;
    float4 v = *reinterpret_cast<const float4*>(&Bbase[row * 64 + c4]);
    Bs[row][c4 + 0] = v.x * SC; Bs[row][c4 + 1] = v.y * SC;
    Bs[row][c4 + 2] = v.z * SC; Bs[row][c4 + 3] = v.w * SC;
  }
  if (t < 64) qs[t] = q[t];
  __syncthreads();

  const float* Abase = Ar + bh * 16384 + t * 64;
  float acc[32];
#pragma unroll
  for (int j = 0; j < 32; ++j) acc[j] = 0.f;

#pragma unroll 1
  for (int c4 = 0; c4 < 64; c4 += 4) {
    float4 av = *reinterpret_cast<const float4*>(&Abase[c4]);
    float aa[4] = {av.x, av.y, av.z, av.w};
#pragma unroll
    for (int cc = 0; cc < 4; ++cc) {
      float a = aa[cc];
      float qc = qs[c4 + cc];
#pragma unroll
      for (int j = 0; j < 32; ++j) {
        float x = a * Bs[j][c4 + cc];     // = 2*log2e * (A_ic * B_jc)
        float e = fast_exp2(x);           // e^{2y}
        float s = (e - 1.f) * fast_rcp(e + 1.f);  // tanh(y)
        acc[j] = fmaf(s, qc, acc[j]);
      }
    }
  }

  float rsum = 0.f;
#pragma unroll
  for (int j = 0; j < 32; ++j) rsum += acc[j];
  rowpart[(bh * 8 + jblk) * 256 + t] = rsum;

  int lane = t & 63, w = t >> 6;
#pragma unroll
  for (int j = 0; j < 32; ++j) {
    float v = acc[j];
#pragma unroll
    for (int off = 32; off >= 1; off >>= 1) v += __shfl_xor(v, off);
    if (lane == 0) cpart[w][j] = v;
  }
  __syncthreads();
  if (t < 32) {
    colsum[bh * 256 + jblk * 32 + t] =
        cpart[0][t] + cpart[1][t] + cpart[2][t] + cpart[3][t];
  }
}

// ---------------------------------------------------------------------------
// Stage 3: per (b,h): softmax over the 256 row-means / col-means, write temps
// to ws, and compute pooled outputs A_p/B_p directly into out[0:8192].
// ---------------------------------------------------------------------------
__global__ __launch_bounds__(256) void softmax_pool_kernel(
    const float* __restrict__ rowpart, const float* __restrict__ colsum,
    const float* __restrict__ A0, const float* __restrict__ B0,
    float* __restrict__ b2a, float* __restrict__ a2b, float* __restrict__ out) {
  int bh = blockIdx.x;
  int b = bh >> 3, h = bh & 7;
  int t = threadIdx.x;
  int lane = t & 63, w = t >> 6;
  __shared__ float redA[4], redB[4], redC[4], redD[4];
  __shared__ float tA[256], tB[256];
  __shared__ float pp[4][64];

  float r = 0.f;
#pragma unroll
  for (int jb = 0; jb < 8; ++jb) r += rowpart[(bh * 8 + jb) * 256 + t];
  r *= (1.f / 256.f);
  float cs = colsum[bh * 256 + t] * (1.f / 256.f);

  float mr = r, mc = cs;
#pragma unroll
  for (int off = 32; off >= 1; off >>= 1) {
    mr = fmaxf(mr, __shfl_xor(mr, off));
    mc = fmaxf(mc, __shfl_xor(mc, off));
  }
  if (lane == 0) { redA[w] = mr; redB[w] = mc; }
  __syncthreads();
  mr = fmaxf(fmaxf(redA[0], redA[1]), fmaxf(redA[2], redA[3]));
  mc = fmaxf(fmaxf(redB[0], redB[1]), fmaxf(redB[2], redB[3]));

  float er = fast_exp2((r - mr) * LOG2E);
  float ec = fast_exp2((cs - mc) * LOG2E);
  float sr = er, sc = ec;
#pragma unroll
  for (int off = 32; off >= 1; off >>= 1) {
    sr += __shfl_xor(sr, off);
    sc += __shfl_xor(sc, off);
  }
  if (lane == 0) { redC[w] = sr; redD[w] = sc; }
  __syncthreads();
  sr = redC[0] + redC[1] + redC[2] + redC[3];
  sc = redD[0] + redD[1] + redD[2] + redD[3];

  float vb2a = er * fast_rcp(sr);
  float va2b = ec * fast_rcp(sc);
  tA[t] = vb2a; tB[t] = va2b;
  b2a[bh * 256 + t] = vb2a;
  a2b[bh * 256 + t] = va2b;
  __syncthreads();

  // pooling: A_p[b, h*64+c] = sum_i A_heads[b,h,i,c] * tA[i]
  int c = t & 63, iq = t >> 6;
  const float* Ab = A0 + b * 131072 + h * 16384;
  const float* Bb = B0 + b * 131072 + h * 16384;
  float pa = 0.f, pb = 0.f;
#pragma unroll 4
  for (int ii = 0; ii < 64; ++ii) {
    int i = (iq << 6) + ii;
    pa = fmaf(Ab[i * 64 + c], tA[i], pa);
    pb = fmaf(Bb[i * 64 + c], tB[i], pb);
  }
  pp[iq][c] = pa;
  __syncthreads();
  if (t < 64) out[b * 1024 + h * 64 + t] = pp[0][t] + pp[1][t] + pp[2][t] + pp[3][t];
  __syncthreads();
  pp[iq][c] = pb;
  __syncthreads();
  if (t < 64) out[b * 1024 + 512 + h * 64 + t] = pp[0][t] + pp[1][t] + pp[2][t] + pp[3][t];
}

// ---------------------------------------------------------------------------
// Stage 4: out1[b,i] = mean_h temp_b2a ; out2[b,j] = mean_h temp_a2b
// ---------------------------------------------------------------------------
__global__ __launch_bounds__(256) void mean_heads_kernel(
    const float* __restrict__ b2a, const float* __restrict__ a2b,
    float* __restrict__ out) {
  int b = blockIdx.x, t = threadIdx.x;
  float s1 = 0.f, s2 = 0.f;
#pragma unroll
  for (int h = 0; h < 8; ++h) {
    s1 += b2a[(b * 8 + h) * 256 + t];
    s2 += a2b[(b * 8 + h) * 256 + t];
  }
  out[8192 + b * 256 + t] = s1 * 0.125f;
  out[10240 + b * 256 + t] = s2 * 0.125f;
}

extern "C" void kernel_launch(void* const* d_in, const int* in_sizes, int n_in,
                              void* d_out, int out_size, void* d_ws, size_t ws_size,
                              hipStream_t stream) {
  const float* A  = (const float*)d_in[0];
  const float* B  = (const float*)d_in[1];
  const float* W1 = (const float*)d_in[2];
  const float* b1 = (const float*)d_in[3];
  const float* W2 = (const float*)d_in[4];
  const float* b2 = (const float*)d_in[5];
  const float* q  = (const float*)d_in[6];
  float* out = (float*)d_out;
  float* ws = (float*)d_ws;

  float* Ar      = ws;                     // 1,048,576 f
  float* Br      = Ar + (1 << 20);         // 1,048,576 f
  float* rowpart = Br + (1 << 20);         // 64*8*256 = 131,072 f
  float* colsum  = rowpart + 64 * 8 * 256; // 16,384 f
  float* b2a     = colsum + 64 * 256;      // 16,384 f
  float* a2b     = b2a + 64 * 256;         // 16,384 f  (total ~9.1 MB)

  gemm_relu_kernel<<<dim3(32, 8, 2), 256, 0, stream>>>(A, W1, b1, Ar, B, W2, b2, Br);
  attmap_kernel<<<dim3(64, 8), 256, 0, stream>>>(Ar, Br, q, rowpart, colsum);
  softmax_pool_kernel<<<64, 256, 0, stream>>>(rowpart, colsum, A, B, b2a, a2b, out);
  mean_heads_kernel<<<8, 256, 0, stream>>>(b2a, a2b, out);
}

// Round 2
// 111.770 us; speedup vs baseline: 1.1592x; 1.1592x over previous
//
#include <hip/hip_runtime.h>

#define LOG2E 1.4426950408889634f

__device__ __forceinline__ float fast_exp2(float x) {
#if __has_builtin(__builtin_amdgcn_exp2f)
  return __builtin_amdgcn_exp2f(x);
#else
  return exp2f(x);
#endif
}
__device__ __forceinline__ float fast_rcp(float x) {
#if __has_builtin(__builtin_amdgcn_rcpf)
  return __builtin_amdgcn_rcpf(x);
#else
  return 1.0f / x;
#endif
}

// ---------------------------------------------------------------------------
// Stage 1: O = relu(X @ W^T + bias).  X:(2048,512) row-major, W:(512,512)
// row-major (so both operands are K-contiguous). 64x64 tile, 4x4 per thread.
// blockIdx.z selects (A,W1,b1)->Ar vs (B,W2,b2)->Br.
// ---------------------------------------------------------------------------
__global__ __launch_bounds__(256) void gemm_relu_kernel(
    const float* __restrict__ Xa, const float* __restrict__ Wa,
    const float* __restrict__ ba, float* __restrict__ Oa,
    const float* __restrict__ Xb, const float* __restrict__ Wb,
    const float* __restrict__ bb, float* __restrict__ Ob) {
  const int K = 512, N = 512;
  const float* X = blockIdx.z ? Xb : Xa;
  const float* W = blockIdx.z ? Wb : Wa;
  const float* bias = blockIdx.z ? bb : ba;
  float* O = blockIdx.z ? Ob : Oa;

  __shared__ __align__(16) float Xs[32][68];
  __shared__ __align__(16) float Ws[32][68];

  int t = threadIdx.x;
  int tm = t & 15, tn = t >> 4;
  int m0 = blockIdx.x * 64, n0 = blockIdx.y * 64;

  float acc[4][4] = {};

  for (int k0 = 0; k0 < K; k0 += 32) {
#pragma unroll
    for (int l = 0; l < 2; ++l) {
      int f = t + l * 256;
      int row = f >> 3;
      int kq = (f & 7) << 2;
      float4 xv = *reinterpret_cast<const float4*>(&X[(m0 + row) * K + k0 + kq]);
      Xs[kq + 0][row] = xv.x; Xs[kq + 1][row] = xv.y;
      Xs[kq + 2][row] = xv.z; Xs[kq + 3][row] = xv.w;
      float4 wv = *reinterpret_cast<const float4*>(&W[(n0 + row) * K + k0 + kq]);
      Ws[kq + 0][row] = wv.x; Ws[kq + 1][row] = wv.y;
      Ws[kq + 2][row] = wv.z; Ws[kq + 3][row] = wv.w;
    }
    __syncthreads();
#pragma unroll
    for (int kk = 0; kk < 32; ++kk) {
      float4 av = *reinterpret_cast<const float4*>(&Xs[kk][tm << 2]);
      float4 bv = *reinterpret_cast<const float4*>(&Ws[kk][tn << 2]);
      acc[0][0] = fmaf(av.x, bv.x, acc[0][0]);
      acc[0][1] = fmaf(av.x, bv.y, acc[0][1]);
      acc[0][2] = fmaf(av.x, bv.z, acc[0][2]);
      acc[0][3] = fmaf(av.x, bv.w, acc[0][3]);
      acc[1][0] = fmaf(av.y, bv.x, acc[1][0]);
      acc[1][1] = fmaf(av.y, bv.y, acc[1][1]);
      acc[1][2] = fmaf(av.y, bv.z, acc[1][2]);
      acc[1][3] = fmaf(av.y, bv.w, acc[1][3]);
      acc[2][0] = fmaf(av.z, bv.x, acc[2][0]);
      acc[2][1] = fmaf(av.z, bv.y, acc[2][1]);
      acc[2][2] = fmaf(av.z, bv.z, acc[2][2]);
      acc[2][3] = fmaf(av.z, bv.w, acc[2][3]);
      acc[3][0] = fmaf(av.w, bv.x, acc[3][0]);
      acc[3][1] = fmaf(av.w, bv.y, acc[3][1]);
      acc[3][2] = fmaf(av.w, bv.z, acc[3][2]);
      acc[3][3] = fmaf(av.w, bv.w, acc[3][3]);
    }
    __syncthreads();
  }

#pragma unroll
  for (int i = 0; i < 4; ++i) {
#pragma unroll
    for (int j = 0; j < 4; ++j) {
      int n = n0 + (tn << 2) + j;
      float v = acc[i][j] + bias[n];
      O[(m0 + (tm << 2) + i) * N + n] = v > 0.f ? v : 0.f;
    }
  }
}

// ---------------------------------------------------------------------------
// Stage 2: M[i,j] = sum_c tanh(A_[i,c]*B_[j,c]) * q[c], reduced two ways.
// 512-thread blocks: group g = t>>8 owns 16 j's; i = t&255.
// B slab (32 j x 64 c) staged in LDS with 2*log2e folded in.
// ~50% of B entries are exactly 0 (ReLU); B[j][c] is wave-uniform, so a
// readfirstlane scalar branch skips the tanh body with zero divergence.
// ---------------------------------------------------------------------------
__global__ __launch_bounds__(512, 4) void attmap_kernel(
    const float* __restrict__ Ar, const float* __restrict__ Br,
    const float* __restrict__ q, float* __restrict__ rowpart,
    float* __restrict__ colsum) {
  int bh = blockIdx.x, jblk = blockIdx.y;
  int t = threadIdx.x;
  int g = t >> 8;
  int i = t & 255;
  __shared__ __align__(16) float Bs[32][64];
  __shared__ __align__(16) float qs[64];
  __shared__ float cpart[8][16];
  __shared__ float rtmp[512];
  const float SC = 2.8853900817779268f;  // 2 * log2(e)

  const float* Bbase = Br + bh * 16384 + jblk * 2048;
  {
    int row = t >> 4, c4 = (t & 15) << 2;  // 512 float4 slots: 32 rows x 16 quads
    float4 v = *reinterpret_cast<const float4*>(&Bbase[row * 64 + c4]);
    Bs[row][c4 + 0] = v.x * SC; Bs[row][c4 + 1] = v.y * SC;
    Bs[row][c4 + 2] = v.z * SC; Bs[row][c4 + 3] = v.w * SC;
  }
  if (t < 64) qs[t] = q[t];
  __syncthreads();

  const float* Abase = Ar + bh * 16384 + i * 64;
  float acc[16];
#pragma unroll
  for (int j = 0; j < 16; ++j) acc[j] = 0.f;
  const int jbase = g << 4;

#pragma unroll 1
  for (int c4 = 0; c4 < 64; c4 += 4) {
    float4 av = *reinterpret_cast<const float4*>(&Abase[c4]);
    float4 qv = *reinterpret_cast<const float4*>(&qs[c4]);
    float aa[4] = {av.x, av.y, av.z, av.w};
    float qq[4] = {qv.x, qv.y, qv.z, qv.w};
#pragma unroll
    for (int j = 0; j < 16; ++j) {
      float4 bv = *reinterpret_cast<const float4*>(&Bs[jbase + j][c4]);
      float bb[4] = {bv.x, bv.y, bv.z, bv.w};
#pragma unroll
      for (int cc = 0; cc < 4; ++cc) {
        // B value is wave-uniform; scalar test -> s_cbranch skips the body.
        if (__builtin_amdgcn_readfirstlane(__float_as_uint(bb[cc])) != 0u) {
          float e = fast_exp2(aa[cc] * bb[cc]);    // e^{2y}, y = A*B
          float r = fast_rcp(e + 1.f);
          float tt = fmaf(e, r, -r);               // tanh(y) = (e-1)/(e+1)
          acc[j] = fmaf(tt, qq[cc], acc[j]);
        }
      }
    }
  }

  float rsum = 0.f;
#pragma unroll
  for (int j = 0; j < 16; ++j) rsum += acc[j];
  rtmp[t] = rsum;

  int lane = t & 63, w = t >> 6;
#pragma unroll
  for (int j = 0; j < 16; ++j) {
    float v = acc[j];
#pragma unroll
    for (int off = 32; off >= 1; off >>= 1) v += __shfl_xor(v, off);
    if (lane == 0) cpart[w][j] = v;
  }
  __syncthreads();
  if (t < 256) {
    rowpart[(bh * 8 + jblk) * 256 + t] = rtmp[t] + rtmp[t + 256];
  } else if (t < 288) {
    int jj = t - 256;
    int wb = (jj >> 4) << 2;  // waves 0-3 for j 0-15, waves 4-7 for j 16-31
    int jl = jj & 15;
    colsum[bh * 256 + jblk * 32 + jj] =
        cpart[wb + 0][jl] + cpart[wb + 1][jl] + cpart[wb + 2][jl] + cpart[wb + 3][jl];
  }
}

// ---------------------------------------------------------------------------
// Stage 3: per (b,h): softmax over 256 row/col means, write temps to ws,
// pooled outputs into out[0:8192].
// ---------------------------------------------------------------------------
__global__ __launch_bounds__(256) void softmax_pool_kernel(
    const float* __restrict__ rowpart, const float* __restrict__ colsum,
    const float* __restrict__ A0, const float* __restrict__ B0,
    float* __restrict__ b2a, float* __restrict__ a2b, float* __restrict__ out) {
  int bh = blockIdx.x;
  int b = bh >> 3, h = bh & 7;
  int t = threadIdx.x;
  int lane = t & 63, w = t >> 6;
  __shared__ float redA[4], redB[4], redC[4], redD[4];
  __shared__ float tA[256], tB[256];
  __shared__ float pp[4][64];

  float r = 0.f;
#pragma unroll
  for (int jb = 0; jb < 8; ++jb) r += rowpart[(bh * 8 + jb) * 256 + t];
  r *= (1.f / 256.f);
  float cs = colsum[bh * 256 + t] * (1.f / 256.f);

  float mr = r, mc = cs;
#pragma unroll
  for (int off = 32; off >= 1; off >>= 1) {
    mr = fmaxf(mr, __shfl_xor(mr, off));
    mc = fmaxf(mc, __shfl_xor(mc, off));
  }
  if (lane == 0) { redA[w] = mr; redB[w] = mc; }
  __syncthreads();
  mr = fmaxf(fmaxf(redA[0], redA[1]), fmaxf(redA[2], redA[3]));
  mc = fmaxf(fmaxf(redB[0], redB[1]), fmaxf(redB[2], redB[3]));

  float er = fast_exp2((r - mr) * LOG2E);
  float ec = fast_exp2((cs - mc) * LOG2E);
  float sr = er, sc = ec;
#pragma unroll
  for (int off = 32; off >= 1; off >>= 1) {
    sr += __shfl_xor(sr, off);
    sc += __shfl_xor(sc, off);
  }
  if (lane == 0) { redC[w] = sr; redD[w] = sc; }
  __syncthreads();
  sr = redC[0] + redC[1] + redC[2] + redC[3];
  sc = redD[0] + redD[1] + redD[2] + redD[3];

  float vb2a = er * fast_rcp(sr);
  float va2b = ec * fast_rcp(sc);
  tA[t] = vb2a; tB[t] = va2b;
  b2a[bh * 256 + t] = vb2a;
  a2b[bh * 256 + t] = va2b;
  __syncthreads();

  int c = t & 63, iq = t >> 6;
  const float* Ab = A0 + b * 131072 + h * 16384;
  const float* Bb = B0 + b * 131072 + h * 16384;
  float pa = 0.f, pb = 0.f;
#pragma unroll 4
  for (int ii = 0; ii < 64; ++ii) {
    int i = (iq << 6) + ii;
    pa = fmaf(Ab[i * 64 + c], tA[i], pa);
    pb = fmaf(Bb[i * 64 + c], tB[i], pb);
  }
  pp[iq][c] = pa;
  __syncthreads();
  if (t < 64) out[b * 1024 + h * 64 + t] = pp[0][t] + pp[1][t] + pp[2][t] + pp[3][t];
  __syncthreads();
  pp[iq][c] = pb;
  __syncthreads();
  if (t < 64) out[b * 1024 + 512 + h * 64 + t] = pp[0][t] + pp[1][t] + pp[2][t] + pp[3][t];
}

// ---------------------------------------------------------------------------
// Stage 4: out1[b,i] = mean_h temp_b2a ; out2[b,j] = mean_h temp_a2b
// ---------------------------------------------------------------------------
__global__ __launch_bounds__(256) void mean_heads_kernel(
    const float* __restrict__ b2a, const float* __restrict__ a2b,
    float* __restrict__ out) {
  int b = blockIdx.x, t = threadIdx.x;
  float s1 = 0.f, s2 = 0.f;
#pragma unroll
  for (int h = 0; h < 8; ++h) {
    s1 += b2a[(b * 8 + h) * 256 + t];
    s2 += a2b[(b * 8 + h) * 256 + t];
  }
  out[8192 + b * 256 + t] = s1 * 0.125f;
  out[10240 + b * 256 + t] = s2 * 0.125f;
}

extern "C" void kernel_launch(void* const* d_in, const int* in_sizes, int n_in,
                              void* d_out, int out_size, void* d_ws, size_t ws_size,
                              hipStream_t stream) {
  const float* A  = (const float*)d_in[0];
  const float* B  = (const float*)d_in[1];
  const float* W1 = (const float*)d_in[2];
  const float* b1 = (const float*)d_in[3];
  const float* W2 = (const float*)d_in[4];
  const float* b2 = (const float*)d_in[5];
  const float* q  = (const float*)d_in[6];
  float* out = (float*)d_out;
  float* ws = (float*)d_ws;

  float* Ar      = ws;                     // 1,048,576 f
  float* Br      = Ar + (1 << 20);         // 1,048,576 f
  float* rowpart = Br + (1 << 20);         // 64*8*256 = 131,072 f
  float* colsum  = rowpart + 64 * 8 * 256; // 16,384 f
  float* b2a     = colsum + 64 * 256;      // 16,384 f
  float* a2b     = b2a + 64 * 256;         // 16,384 f  (total ~8.7 MB)

  gemm_relu_kernel<<<dim3(32, 8, 2), 256, 0, stream>>>(A, W1, b1, Ar, B, W2, b2, Br);
  attmap_kernel<<<dim3(64, 8), 512, 0, stream>>>(Ar, Br, q, rowpart, colsum);
  softmax_pool_kernel<<<64, 256, 0, stream>>>(rowpart, colsum, A, B, b2a, a2b, out);
  mean_heads_kernel<<<8, 256, 0, stream>>>(b2a, a2b, out);
}

// Round 3
// 85.690 us; speedup vs baseline: 1.5120x; 1.3043x over previous
//
#include <hip/hip_runtime.h>
#include <hip/hip_bf16.h>

#define LOG2E 1.4426950408889634f

typedef __attribute__((ext_vector_type(8))) short short8b;   // 8 bf16 (4 VGPR)
typedef __attribute__((ext_vector_type(4))) short short4b;   // 4 bf16 (8 B)
typedef __attribute__((ext_vector_type(4))) float f32x4;

__device__ __forceinline__ float fast_exp2(float x) {
#if __has_builtin(__builtin_amdgcn_exp2f)
  return __builtin_amdgcn_exp2f(x);
#else
  return exp2f(x);
#endif
}
__device__ __forceinline__ float fast_rcp(float x) {
#if __has_builtin(__builtin_amdgcn_rcpf)
  return __builtin_amdgcn_rcpf(x);
#else
  return 1.0f / x;
#endif
}
__device__ __forceinline__ short f2bf(float f) {
  __hip_bfloat16 h = __float2bfloat16(f);
  return *reinterpret_cast<short*>(&h);
}

// ---------------------------------------------------------------------------
// Stage 1: O = relu(X @ W^T + bias) via bf16 MFMA (f32 accumulate).
// X:(2048,512), W:(512,512), both K-contiguous row-major -> identical
// fragment staging for A and B operands. Tile 128x64, 4 waves (2x2),
// per-wave 64x32 = 4x2 frags of 16x16, K-step 32 (one mfma_16x16x32 per frag).
// LDS rows padded to 40 bf16 (80 B) -> 2-way-max bank aliasing (free).
// grid (16, 8, 2): z selects (A,W1,b1)->Ar vs (B,W2,b2)->Br.
// ---------------------------------------------------------------------------
__global__ __launch_bounds__(256) void gemm_mfma_kernel(
    const float* __restrict__ Xa, const float* __restrict__ Wa,
    const float* __restrict__ ba, float* __restrict__ Oa,
    const float* __restrict__ Xb, const float* __restrict__ Wb,
    const float* __restrict__ bb, float* __restrict__ Ob) {
  const float* X = blockIdx.z ? Xb : Xa;
  const float* W = blockIdx.z ? Wb : Wa;
  const float* bias = blockIdx.z ? bb : ba;
  float* O = blockIdx.z ? Ob : Oa;

  __shared__ __align__(16) short As[128 * 40];  // 128 rows x 32 bf16 (+8 pad)
  __shared__ __align__(16) short Ws[64 * 40];   // 64 rows x 32 bf16 (+8 pad)

  int t = threadIdx.x;
  int m0 = blockIdx.x * 128, n0 = blockIdx.y * 64;
  int l = t & 63, w = t >> 6;
  int wm = (w >> 1) * 64, wn = (w & 1) * 32;
  int lr = l & 15, ko = (l >> 4) * 8;

  f32x4 acc[4][2];
#pragma unroll
  for (int m = 0; m < 4; ++m)
#pragma unroll
    for (int n = 0; n < 2; ++n) acc[m][n] = f32x4{0.f, 0.f, 0.f, 0.f};

  for (int k0 = 0; k0 < 512; k0 += 32) {
    // stage A-tile: 128x32 f32 = 1024 float4 slots, 4 per thread
#pragma unroll
    for (int s = 0; s < 4; ++s) {
      int slot = t + s * 256;
      int row = slot >> 3, q = (slot & 7) << 2;
      float4 v = *reinterpret_cast<const float4*>(&X[(m0 + row) * 512 + k0 + q]);
      short4b sv = {f2bf(v.x), f2bf(v.y), f2bf(v.z), f2bf(v.w)};
      *reinterpret_cast<short4b*>(&As[row * 40 + q]) = sv;
    }
    // stage W-tile: 64x32 f32 = 512 slots, 2 per thread
#pragma unroll
    for (int s = 0; s < 2; ++s) {
      int slot = t + s * 256;
      int row = slot >> 3, q = (slot & 7) << 2;
      float4 v = *reinterpret_cast<const float4*>(&W[(n0 + row) * 512 + k0 + q]);
      short4b sv = {f2bf(v.x), f2bf(v.y), f2bf(v.z), f2bf(v.w)};
      *reinterpret_cast<short4b*>(&Ws[row * 40 + q]) = sv;
    }
    __syncthreads();

    short8b afr[4], bfr[2];
#pragma unroll
    for (int m = 0; m < 4; ++m)
      afr[m] = *reinterpret_cast<const short8b*>(&As[(wm + m * 16 + lr) * 40 + ko]);
#pragma unroll
    for (int n = 0; n < 2; ++n)
      bfr[n] = *reinterpret_cast<const short8b*>(&Ws[(wn + n * 16 + lr) * 40 + ko]);
#pragma unroll
    for (int m = 0; m < 4; ++m)
#pragma unroll
      for (int n = 0; n < 2; ++n)
        acc[m][n] = __builtin_amdgcn_mfma_f32_16x16x32_bf16(afr[m], bfr[n], acc[m][n], 0, 0, 0);
    __syncthreads();
  }

  // epilogue: bias + relu, f32 store. C/D layout: col = lane&15, row = (lane>>4)*4 + r
#pragma unroll
  for (int n = 0; n < 2; ++n) {
    int col = n0 + wn + n * 16 + lr;
    float bv = bias[col];
#pragma unroll
    for (int m = 0; m < 4; ++m) {
      int rbase = m0 + wm + m * 16 + (l >> 4) * 4;
#pragma unroll
      for (int r = 0; r < 4; ++r) {
        float v = acc[m][n][r] + bv;
        O[(rbase + r) * 512 + col] = v > 0.f ? v : 0.f;
      }
    }
  }
}

// ---------------------------------------------------------------------------
// Stage 2: M'[i,j] = sum_c (-2 q_c) * rcp(exp(2 A_ic B_jc) + 1)
// (true M = Sum_c q_c + M'; the constant shift cancels in both softmaxes.)
// Branch-free 5-instr body: mul, exp2, add, rcp, fma.  Exact for a=0 or b=0.
// grid (64 bh, 8 jblk, 2 cblk); 512 threads: group g=t>>8 owns 16 j's, i=t&255.
// ---------------------------------------------------------------------------
__global__ __launch_bounds__(512, 6) void attmap_kernel(
    const float* __restrict__ Ar, const float* __restrict__ Br,
    const float* __restrict__ q, float* __restrict__ rowpart,
    float* __restrict__ colsum) {
  int bh = blockIdx.x, jblk = blockIdx.y, cblk = blockIdx.z;
  int t = threadIdx.x;
  int g = t >> 8;
  int i = t & 255;
  __shared__ __align__(16) float Bs[32][32];
  __shared__ __align__(16) float m2qs[32];
  __shared__ float cpart[8][16];
  __shared__ float rtmp[512];
  const float SC = 2.8853900817779268f;  // 2 * log2(e)

  const float* Bbase = Br + bh * 16384 + jblk * 2048 + cblk * 32;
  if (t < 256) {
    int row = t >> 3, c4 = (t & 7) << 2;  // 32 rows x 8 quads
    float4 v = *reinterpret_cast<const float4*>(&Bbase[row * 64 + c4]);
    Bs[row][c4 + 0] = v.x * SC; Bs[row][c4 + 1] = v.y * SC;
    Bs[row][c4 + 2] = v.z * SC; Bs[row][c4 + 3] = v.w * SC;
  } else if (t < 264) {
    int c4 = (t - 256) << 2;
    float4 v = *reinterpret_cast<const float4*>(&q[cblk * 32 + c4]);
    m2qs[c4 + 0] = -2.f * v.x; m2qs[c4 + 1] = -2.f * v.y;
    m2qs[c4 + 2] = -2.f * v.z; m2qs[c4 + 3] = -2.f * v.w;
  }
  __syncthreads();

  const float* Abase = Ar + bh * 16384 + i * 64 + cblk * 32;
  float acc[16];
#pragma unroll
  for (int j = 0; j < 16; ++j) acc[j] = 0.f;
  const int jbase = g << 4;

  float4 av = *reinterpret_cast<const float4*>(&Abase[0]);
#pragma unroll 1
  for (int c4 = 0; c4 < 32; c4 += 4) {
    float4 avn;
    if (c4 + 4 < 32) avn = *reinterpret_cast<const float4*>(&Abase[c4 + 4]);
    float4 mq = *reinterpret_cast<const float4*>(&m2qs[c4]);
    float aa[4] = {av.x, av.y, av.z, av.w};
    float qq[4] = {mq.x, mq.y, mq.z, mq.w};
#pragma unroll
    for (int j = 0; j < 16; ++j) {
      float4 bv = *reinterpret_cast<const float4*>(&Bs[jbase + j][c4]);
      float bb[4] = {bv.x, bv.y, bv.z, bv.w};
#pragma unroll
      for (int cc = 0; cc < 4; ++cc) {
        float e = fast_exp2(aa[cc] * bb[cc]);   // e^{2ab}
        float r = fast_rcp(e + 1.f);
        acc[j] = fmaf(qq[cc], r, acc[j]);       // += -2q * r
      }
    }
    av = avn;
  }

  float rsum = 0.f;
#pragma unroll
  for (int j = 0; j < 16; ++j) rsum += acc[j];
  rtmp[t] = rsum;

  int lane = t & 63, w = t >> 6;
#pragma unroll
  for (int j = 0; j < 16; ++j) {
    float v = acc[j];
#pragma unroll
    for (int off = 32; off >= 1; off >>= 1) v += __shfl_xor(v, off);
    if (lane == 0) cpart[w][j] = v;
  }
  __syncthreads();
  if (t < 256) {
    rowpart[(cblk * 512 + bh * 8 + jblk) * 256 + t] = rtmp[t] + rtmp[t + 256];
  } else if (t < 288) {
    int jj = t - 256;
    int wb = (jj >> 4) << 2;  // waves 0-3: j 0-15 (g=0); waves 4-7: j 16-31
    int jl = jj & 15;
    colsum[cblk * 16384 + bh * 256 + jblk * 32 + jj] =
        cpart[wb + 0][jl] + cpart[wb + 1][jl] + cpart[wb + 2][jl] + cpart[wb + 3][jl];
  }
}

// ---------------------------------------------------------------------------
// Stage 3: per (b,h): softmax over 256 row/col means (16 row-partials, 2 col
// partials), write temps to ws, pooled outputs into out[0:8192].
// ---------------------------------------------------------------------------
__global__ __launch_bounds__(256) void softmax_pool_kernel(
    const float* __restrict__ rowpart, const float* __restrict__ colsum,
    const float* __restrict__ A0, const float* __restrict__ B0,
    float* __restrict__ b2a, float* __restrict__ a2b, float* __restrict__ out) {
  int bh = blockIdx.x;
  int b = bh >> 3, h = bh & 7;
  int t = threadIdx.x;
  int lane = t & 63, w = t >> 6;
  __shared__ float redA[4], redB[4], redC[4], redD[4];
  __shared__ float tA[256], tB[256];
  __shared__ float pp[4][64];

  float r = 0.f;
#pragma unroll
  for (int cb = 0; cb < 2; ++cb)
#pragma unroll
    for (int jb = 0; jb < 8; ++jb)
      r += rowpart[(cb * 512 + bh * 8 + jb) * 256 + t];
  r *= (1.f / 256.f);
  float cs = (colsum[bh * 256 + t] + colsum[16384 + bh * 256 + t]) * (1.f / 256.f);

  float mr = r, mc = cs;
#pragma unroll
  for (int off = 32; off >= 1; off >>= 1) {
    mr = fmaxf(mr, __shfl_xor(mr, off));
    mc = fmaxf(mc, __shfl_xor(mc, off));
  }
  if (lane == 0) { redA[w] = mr; redB[w] = mc; }
  __syncthreads();
  mr = fmaxf(fmaxf(redA[0], redA[1]), fmaxf(redA[2], redA[3]));
  mc = fmaxf(fmaxf(redB[0], redB[1]), fmaxf(redB[2], redB[3]));

  float er = fast_exp2((r - mr) * LOG2E);
  float ec = fast_exp2((cs - mc) * LOG2E);
  float sr = er, sc = ec;
#pragma unroll
  for (int off = 32; off >= 1; off >>= 1) {
    sr += __shfl_xor(sr, off);
    sc += __shfl_xor(sc, off);
  }
  if (lane == 0) { redC[w] = sr; redD[w] = sc; }
  __syncthreads();
  sr = redC[0] + redC[1] + redC[2] + redC[3];
  sc = redD[0] + redD[1] + redD[2] + redD[3];

  float vb2a = er * fast_rcp(sr);
  float va2b = ec * fast_rcp(sc);
  tA[t] = vb2a; tB[t] = va2b;
  b2a[bh * 256 + t] = vb2a;
  a2b[bh * 256 + t] = va2b;
  __syncthreads();

  int c = t & 63, iq = t >> 6;
  const float* Ab = A0 + b * 131072 + h * 16384;
  const float* Bb = B0 + b * 131072 + h * 16384;
  float pa = 0.f, pb = 0.f;
#pragma unroll 4
  for (int ii = 0; ii < 64; ++ii) {
    int i = (iq << 6) + ii;
    pa = fmaf(Ab[i * 64 + c], tA[i], pa);
    pb = fmaf(Bb[i * 64 + c], tB[i], pb);
  }
  pp[iq][c] = pa;
  __syncthreads();
  if (t < 64) out[b * 1024 + h * 64 + t] = pp[0][t] + pp[1][t] + pp[2][t] + pp[3][t];
  __syncthreads();
  pp[iq][c] = pb;
  __syncthreads();
  if (t < 64) out[b * 1024 + 512 + h * 64 + t] = pp[0][t] + pp[1][t] + pp[2][t] + pp[3][t];
}

// ---------------------------------------------------------------------------
// Stage 4: out1[b,i] = mean_h temp_b2a ; out2[b,j] = mean_h temp_a2b
// ---------------------------------------------------------------------------
__global__ __launch_bounds__(256) void mean_heads_kernel(
    const float* __restrict__ b2a, const float* __restrict__ a2b,
    float* __restrict__ out) {
  int b = blockIdx.x, t = threadIdx.x;
  float s1 = 0.f, s2 = 0.f;
#pragma unroll
  for (int h = 0; h < 8; ++h) {
    s1 += b2a[(b * 8 + h) * 256 + t];
    s2 += a2b[(b * 8 + h) * 256 + t];
  }
  out[8192 + b * 256 + t] = s1 * 0.125f;
  out[10240 + b * 256 + t] = s2 * 0.125f;
}

extern "C" void kernel_launch(void* const* d_in, const int* in_sizes, int n_in,
                              void* d_out, int out_size, void* d_ws, size_t ws_size,
                              hipStream_t stream) {
  const float* A  = (const float*)d_in[0];
  const float* B  = (const float*)d_in[1];
  const float* W1 = (const float*)d_in[2];
  const float* b1 = (const float*)d_in[3];
  const float* W2 = (const float*)d_in[4];
  const float* b2 = (const float*)d_in[5];
  const float* q  = (const float*)d_in[6];
  float* out = (float*)d_out;
  float* ws = (float*)d_ws;

  float* Ar      = ws;                         // 1,048,576 f
  float* Br      = Ar + (1 << 20);             // 1,048,576 f
  float* rowpart = Br + (1 << 20);             // 2*64*8*256 = 262,144 f
  float* colsum  = rowpart + 2 * 64 * 8 * 256; // 2*64*256 = 32,768 f
  float* b2a     = ws;                         // alias Ar (dead after attmap)
  float* a2b     = ws + 16384;                 // 16,384 f  (total ~9.6 MB)

  gemm_mfma_kernel<<<dim3(16, 8, 2), 256, 0, stream>>>(A, W1, b1, Ar, B, W2, b2, Br);
  attmap_kernel<<<dim3(64, 8, 2), 512, 0, stream>>>(Ar, Br, q, rowpart, colsum);
  softmax_pool_kernel<<<64, 256, 0, stream>>>(rowpart, colsum, A, B, b2a, a2b, out);
  mean_heads_kernel<<<8, 256, 0, stream>>>(b2a, a2b, out);
}

// Round 4
// 77.762 us; speedup vs baseline: 1.6661x; 1.1019x over previous
//
#include <hip/hip_runtime.h>
#include <hip/hip_bf16.h>

#define LOG2E 1.4426950408889634f
#define SC2   2.8853900817779268f   // 2*log2(e)

typedef __attribute__((ext_vector_type(8))) short short8b;   // 8 bf16 (4 VGPR)
typedef __attribute__((ext_vector_type(4))) short short4b;   // 4 bf16 (8 B)
typedef __attribute__((ext_vector_type(4))) float f32x4;

__device__ __forceinline__ float fast_exp2(float x) {
#if __has_builtin(__builtin_amdgcn_exp2f)
  return __builtin_amdgcn_exp2f(x);
#else
  return exp2f(x);
#endif
}
__device__ __forceinline__ float fast_rcp(float x) {
#if __has_builtin(__builtin_amdgcn_rcpf)
  return __builtin_amdgcn_rcpf(x);
#else
  return 1.0f / x;
#endif
}
__device__ __forceinline__ short f2bf(float f) {
  __hip_bfloat16 h = __float2bfloat16(f);
  return *reinterpret_cast<short*>(&h);
}

// ---------------------------------------------------------------------------
// Stage 1: O = relu(X @ W^T + bias) via bf16 MFMA (f32 accumulate).
// Tile 128x64, 4 waves (2x2), per-wave 64x32 = 4x2 frags of 16x16.
// ---------------------------------------------------------------------------
__global__ __launch_bounds__(256) void gemm_mfma_kernel(
    const float* __restrict__ Xa, const float* __restrict__ Wa,
    const float* __restrict__ ba, float* __restrict__ Oa,
    const float* __restrict__ Xb, const float* __restrict__ Wb,
    const float* __restrict__ bb, float* __restrict__ Ob) {
  const float* X = blockIdx.z ? Xb : Xa;
  const float* W = blockIdx.z ? Wb : Wa;
  const float* bias = blockIdx.z ? bb : ba;
  float* O = blockIdx.z ? Ob : Oa;

  __shared__ __align__(16) short As[128 * 40];  // 128 rows x 32 bf16 (+8 pad)
  __shared__ __align__(16) short Ws[64 * 40];

  int t = threadIdx.x;
  int m0 = blockIdx.x * 128, n0 = blockIdx.y * 64;
  int l = t & 63, w = t >> 6;
  int wm = (w >> 1) * 64, wn = (w & 1) * 32;
  int lr = l & 15, ko = (l >> 4) * 8;

  f32x4 acc[4][2];
#pragma unroll
  for (int m = 0; m < 4; ++m)
#pragma unroll
    for (int n = 0; n < 2; ++n) acc[m][n] = f32x4{0.f, 0.f, 0.f, 0.f};

  for (int k0 = 0; k0 < 512; k0 += 32) {
#pragma unroll
    for (int s = 0; s < 4; ++s) {
      int slot = t + s * 256;
      int row = slot >> 3, q = (slot & 7) << 2;
      float4 v = *reinterpret_cast<const float4*>(&X[(m0 + row) * 512 + k0 + q]);
      short4b sv = {f2bf(v.x), f2bf(v.y), f2bf(v.z), f2bf(v.w)};
      *reinterpret_cast<short4b*>(&As[row * 40 + q]) = sv;
    }
#pragma unroll
    for (int s = 0; s < 2; ++s) {
      int slot = t + s * 256;
      int row = slot >> 3, q = (slot & 7) << 2;
      float4 v = *reinterpret_cast<const float4*>(&W[(n0 + row) * 512 + k0 + q]);
      short4b sv = {f2bf(v.x), f2bf(v.y), f2bf(v.z), f2bf(v.w)};
      *reinterpret_cast<short4b*>(&Ws[row * 40 + q]) = sv;
    }
    __syncthreads();

    short8b afr[4], bfr[2];
#pragma unroll
    for (int m = 0; m < 4; ++m)
      afr[m] = *reinterpret_cast<const short8b*>(&As[(wm + m * 16 + lr) * 40 + ko]);
#pragma unroll
    for (int n = 0; n < 2; ++n)
      bfr[n] = *reinterpret_cast<const short8b*>(&Ws[(wn + n * 16 + lr) * 40 + ko]);
#pragma unroll
    for (int m = 0; m < 4; ++m)
#pragma unroll
      for (int n = 0; n < 2; ++n)
        acc[m][n] = __builtin_amdgcn_mfma_f32_16x16x32_bf16(afr[m], bfr[n], acc[m][n], 0, 0, 0);
    __syncthreads();
  }

#pragma unroll
  for (int n = 0; n < 2; ++n) {
    int col = n0 + wn + n * 16 + lr;
    float bv = bias[col];
#pragma unroll
    for (int m = 0; m < 4; ++m) {
      int rbase = m0 + wm + m * 16 + (l >> 4) * 4;
#pragma unroll
      for (int r = 0; r < 4; ++r) {
        float v = acc[m][n][r] + bv;
        O[(rbase + r) * 512 + col] = v > 0.f ? v : 0.f;
      }
    }
  }
}

// ---------------------------------------------------------------------------
// Stage 1.5: per (bh, j) compact the nonzero B entries.
// Pair = (B*2log2e, qm) where qm = -2*q[c] with c packed into the low 6
// mantissa bits (rel perturbation 2^-17 — harmless).  Lists padded to a
// multiple of 4 with exact-zero dummy pairs (contribute exactly 0).
// Also emits Kj = sum_{nz} q_c (needed for the column-softmax shift).
// ---------------------------------------------------------------------------
__global__ __launch_bounds__(256) void compact_kernel(
    const float* __restrict__ Br, const float* __restrict__ q,
    float2* __restrict__ Cb, unsigned* __restrict__ Cnt, float* __restrict__ Ksum) {
  int bh = blockIdx.x;
  int t = threadIdx.x;
  __shared__ float Bls[256 * 65];
  __shared__ float qls[64];
  const float* Bbase = Br + bh * 16384;
#pragma unroll
  for (int it = 0; it < 16; ++it) {
    int idx = it * 256 + t;           // float4 slot: 256 j x 16 quads
    int j = idx >> 4, c4 = (idx & 15) << 2;
    float4 v = *reinterpret_cast<const float4*>(&Bbase[j * 64 + c4]);
    Bls[j * 65 + c4 + 0] = v.x; Bls[j * 65 + c4 + 1] = v.y;
    Bls[j * 65 + c4 + 2] = v.z; Bls[j * 65 + c4 + 3] = v.w;
  }
  if (t < 64) qls[t] = q[t];
  __syncthreads();

  int j = t;
  float2* dst = Cb + (bh * 256 + j) * 64;
  int cnt = 0;
  float K = 0.f;
  for (int c = 0; c < 64; ++c) {
    float v = Bls[j * 65 + c];
    if (v > 0.f) {
      K += qls[c];
      unsigned qb = (__float_as_uint(-2.f * qls[c]) & ~63u) | (unsigned)c;
      dst[cnt] = make_float2(v * SC2, __uint_as_float(qb));
      ++cnt;
    }
  }
  while (cnt & 3) { dst[cnt] = make_float2(0.f, 0.f); ++cnt; }
  Cnt[bh * 256 + j] = (unsigned)cnt;
  Ksum[bh * 256 + j] = K;
}

// ---------------------------------------------------------------------------
// Stage 2 (sparse): M''[i,j] = sum_{s in nz(j)} qm_s * rcp(exp(2 A_ic B_jc)+1)
// (true M = Kj + M''; row-shift cancels, col-shift Kj re-added in stage 3.)
// grid (64 bh, 8 jblk, 2 isplit); 512 threads: group g=t>>7 owns 8 j's,
// i_local = t&127.  A staged [i][c] pad-65 (conflict-free dynamic-c reads);
// pairs broadcast-read (wave-uniform), loop bound wave-uniform.
// ---------------------------------------------------------------------------
__global__ __launch_bounds__(512, 6) void attmap_kernel(
    const float* __restrict__ Ar, const float2* __restrict__ Cb,
    const unsigned* __restrict__ Cnt,
    float* __restrict__ rowpart, float* __restrict__ colsum) {
  int bh = blockIdx.x, jblk = blockIdx.y, isplit = blockIdx.z;
  int t = threadIdx.x;
  int il = t & 127, g = t >> 7;
  __shared__ __align__(16) float Als[128 * 65];
  __shared__ __align__(16) float2 Pls[32 * 64];
  __shared__ unsigned cntls[32];
  __shared__ float red[512];
  __shared__ float cpart[8][8];

  const float* Abase = Ar + bh * 16384 + isplit * 8192;
#pragma unroll
  for (int it = 0; it < 4; ++it) {
    int idx = it * 512 + t;           // float4 slot: 128 i x 16 quads
    int r = idx >> 4, c4 = (idx & 15) << 2;
    float4 v = *reinterpret_cast<const float4*>(&Abase[r * 64 + c4]);
    Als[r * 65 + c4 + 0] = v.x; Als[r * 65 + c4 + 1] = v.y;
    Als[r * 65 + c4 + 2] = v.z; Als[r * 65 + c4 + 3] = v.w;
  }
  {
    const float4* Pb = reinterpret_cast<const float4*>(Cb + (bh * 256 + jblk * 32) * 64);
    float4* Pd = reinterpret_cast<float4*>(Pls);
#pragma unroll
    for (int it = 0; it < 2; ++it) Pd[it * 512 + t] = Pb[it * 512 + t];
  }
  if (t < 32) cntls[t] = Cnt[bh * 256 + jblk * 32 + t];
  __syncthreads();

  const float* Arow = &Als[il * 65];
  float acc[8];
#pragma unroll
  for (int jj = 0; jj < 8; ++jj) acc[jj] = 0.f;

#pragma unroll
  for (int jj = 0; jj < 8; ++jj) {
    int jl = g * 8 + jj;
    int n = (int)cntls[jl];
    const float4* P4 = reinterpret_cast<const float4*>(&Pls[jl * 64]);
    float accj = 0.f;
#pragma unroll 1
    for (int s = 0; s < n; s += 4) {
      float4 u = P4[s >> 1];
      float4 v = P4[(s >> 1) + 1];
      float a0 = Arow[__float_as_uint(u.y) & 63u];
      float a1 = Arow[__float_as_uint(u.w) & 63u];
      float a2 = Arow[__float_as_uint(v.y) & 63u];
      float a3 = Arow[__float_as_uint(v.w) & 63u];
      float e0 = fast_exp2(a0 * u.x);
      float e1 = fast_exp2(a1 * u.z);
      float e2 = fast_exp2(a2 * v.x);
      float e3 = fast_exp2(a3 * v.z);
      float r0 = fast_rcp(e0 + 1.f);
      float r1 = fast_rcp(e1 + 1.f);
      float r2 = fast_rcp(e2 + 1.f);
      float r3 = fast_rcp(e3 + 1.f);
      accj = fmaf(u.y, r0, accj);
      accj = fmaf(u.w, r1, accj);
      accj = fmaf(v.y, r2, accj);
      accj = fmaf(v.w, r3, accj);
    }
    acc[jj] = accj;
  }

  float rs = 0.f;
#pragma unroll
  for (int jj = 0; jj < 8; ++jj) rs += acc[jj];
  red[t] = rs;

  int lane = t & 63, w = t >> 6;
#pragma unroll
  for (int jj = 0; jj < 8; ++jj) {
    float v = acc[jj];
#pragma unroll
    for (int off = 32; off >= 1; off >>= 1) v += __shfl_xor(v, off);
    if (lane == 0) cpart[w][jj] = v;
  }
  __syncthreads();
  if (t < 128) {
    rowpart[(bh * 8 + jblk) * 256 + isplit * 128 + t] =
        red[t] + red[t + 128] + red[t + 256] + red[t + 384];
  } else if (t < 160) {
    int jl = t - 128;
    int gg = jl >> 3, jj = jl & 7;
    colsum[(bh * 2 + isplit) * 256 + jblk * 32 + jl] =
        cpart[2 * gg][jj] + cpart[2 * gg + 1][jj];
  }
}

// ---------------------------------------------------------------------------
// Stage 3: per (bh): softmax over 256 row/col means (+Kj shift on cols),
// temps to ws, pooled outputs into out[0:8192].  512 threads; waves 4-7
// mirror 0-3 through the softmax (tt = t&255), all 8 pool.
// ---------------------------------------------------------------------------
__global__ __launch_bounds__(512) void softmax_pool_kernel(
    const float* __restrict__ rowpart, const float* __restrict__ colsum,
    const float* __restrict__ Ksum,
    const float* __restrict__ A0, const float* __restrict__ B0,
    float* __restrict__ b2a, float* __restrict__ a2b, float* __restrict__ out) {
  int bh = blockIdx.x;
  int b = bh >> 3, h = bh & 7;
  int t = threadIdx.x;
  int tt = t & 255;
  int lane = t & 63, w = (t >> 6) & 3;
  __shared__ float redA[4], redB[4], redC[4], redD[4];
  __shared__ float tA[256], tB[256];
  __shared__ float pp[8][64];

  float r = 0.f;
#pragma unroll
  for (int jb = 0; jb < 8; ++jb) r += rowpart[(bh * 8 + jb) * 256 + tt];
  r *= (1.f / 256.f);
  float cs = Ksum[bh * 256 + tt] +
             (colsum[(bh * 2 + 0) * 256 + tt] + colsum[(bh * 2 + 1) * 256 + tt]) * (1.f / 256.f);

  float mr = r, mc = cs;
#pragma unroll
  for (int off = 32; off >= 1; off >>= 1) {
    mr = fmaxf(mr, __shfl_xor(mr, off));
    mc = fmaxf(mc, __shfl_xor(mc, off));
  }
  if (lane == 0) { redA[w] = mr; redB[w] = mc; }
  __syncthreads();
  mr = fmaxf(fmaxf(redA[0], redA[1]), fmaxf(redA[2], redA[3]));
  mc = fmaxf(fmaxf(redB[0], redB[1]), fmaxf(redB[2], redB[3]));

  float er = fast_exp2((r - mr) * LOG2E);
  float ec = fast_exp2((cs - mc) * LOG2E);
  float sr = er, sc = ec;
#pragma unroll
  for (int off = 32; off >= 1; off >>= 1) {
    sr += __shfl_xor(sr, off);
    sc += __shfl_xor(sc, off);
  }
  if (lane == 0) { redC[w] = sr; redD[w] = sc; }
  __syncthreads();
  sr = redC[0] + redC[1] + redC[2] + redC[3];
  sc = redD[0] + redD[1] + redD[2] + redD[3];

  float vb2a = er * fast_rcp(sr);
  float va2b = ec * fast_rcp(sc);
  tA[tt] = vb2a; tB[tt] = va2b;
  b2a[bh * 256 + tt] = vb2a;
  a2b[bh * 256 + tt] = va2b;
  __syncthreads();

  int c = t & 63, iq = t >> 6;  // 8 groups x 32 i
  const float* Ab = A0 + b * 131072 + h * 16384;
  const float* Bb = B0 + b * 131072 + h * 16384;
  float pa = 0.f, pb = 0.f;
#pragma unroll 4
  for (int ii = 0; ii < 32; ++ii) {
    int i = (iq << 5) + ii;
    pa = fmaf(Ab[i * 64 + c], tA[i], pa);
    pb = fmaf(Bb[i * 64 + c], tB[i], pb);
  }
  pp[iq][c] = pa;
  __syncthreads();
  if (t < 64) {
    float s = 0.f;
#pragma unroll
    for (int k = 0; k < 8; ++k) s += pp[k][t];
    out[b * 1024 + h * 64 + t] = s;
  }
  __syncthreads();
  pp[iq][c] = pb;
  __syncthreads();
  if (t < 64) {
    float s = 0.f;
#pragma unroll
    for (int k = 0; k < 8; ++k) s += pp[k][t];
    out[b * 1024 + 512 + h * 64 + t] = s;
  }
}

// ---------------------------------------------------------------------------
// Stage 4: out1[b,i] = mean_h temp_b2a ; out2[b,j] = mean_h temp_a2b
// ---------------------------------------------------------------------------
__global__ __launch_bounds__(256) void mean_heads_kernel(
    const float* __restrict__ b2a, const float* __restrict__ a2b,
    float* __restrict__ out) {
  int b = blockIdx.x, t = threadIdx.x;
  float s1 = 0.f, s2 = 0.f;
#pragma unroll
  for (int h = 0; h < 8; ++h) {
    s1 += b2a[(b * 8 + h) * 256 + t];
    s2 += a2b[(b * 8 + h) * 256 + t];
  }
  out[8192 + b * 256 + t] = s1 * 0.125f;
  out[10240 + b * 256 + t] = s2 * 0.125f;
}

extern "C" void kernel_launch(void* const* d_in, const int* in_sizes, int n_in,
                              void* d_out, int out_size, void* d_ws, size_t ws_size,
                              hipStream_t stream) {
  const float* A  = (const float*)d_in[0];
  const float* B  = (const float*)d_in[1];
  const float* W1 = (const float*)d_in[2];
  const float* b1 = (const float*)d_in[3];
  const float* W2 = (const float*)d_in[4];
  const float* b2 = (const float*)d_in[5];
  const float* q  = (const float*)d_in[6];
  float* out = (float*)d_out;
  float* ws = (float*)d_ws;

  float*    Ar      = ws;                          // 1,048,576 f
  float*    Brr     = ws + 1048576;                // 1,048,576 f
  float2*   Cb      = (float2*)(ws + 2097152);     // 1,048,576 f2 (8 MB)
  unsigned* Cnt     = (unsigned*)(ws + 4194304);   // 16,384 u32
  float*    Ksum    = ws + 4210688;                // 16,384 f
  float*    rowpart = ws + 4227072;                // 131,072 f
  float*    colsum  = ws + 4358144;                // 32,768 f  (end ~17.6 MB)
  float*    b2a     = ws;                          // alias Ar (dead after attmap)
  float*    a2b     = ws + 16384;

  gemm_mfma_kernel<<<dim3(16, 8, 2), 256, 0, stream>>>(A, W1, b1, Ar, B, W2, b2, Brr);
  compact_kernel<<<64, 256, 0, stream>>>(Brr, q, Cb, Cnt, Ksum);
  attmap_kernel<<<dim3(64, 8, 2), 512, 0, stream>>>(Ar, Cb, Cnt, rowpart, colsum);
  softmax_pool_kernel<<<64, 512, 0, stream>>>(rowpart, colsum, Ksum, A, B, b2a, a2b, out);
  mean_heads_kernel<<<8, 256, 0, stream>>>(b2a, a2b, out);
}

// Round 5
// 73.526 us; speedup vs baseline: 1.7621x; 1.0576x over previous
//
#include <hip/hip_runtime.h>
#include <hip/hip_bf16.h>

#define LOG2E 1.4426950408889634f
#define SC2   2.8853900817779268f   // 2*log2(e)

typedef __attribute__((ext_vector_type(8))) short short8b;   // 8 bf16 (4 VGPR)
typedef __attribute__((ext_vector_type(4))) short short4b;   // 4 bf16 (8 B)
typedef __attribute__((ext_vector_type(4))) float f32x4;

__device__ __forceinline__ float fast_exp2(float x) {
#if __has_builtin(__builtin_amdgcn_exp2f)
  return __builtin_amdgcn_exp2f(x);
#else
  return exp2f(x);
#endif
}
__device__ __forceinline__ float fast_rcp(float x) {
#if __has_builtin(__builtin_amdgcn_rcpf)
  return __builtin_amdgcn_rcpf(x);
#else
  return 1.0f / x;
#endif
}
__device__ __forceinline__ short f2bf(float f) {
  __hip_bfloat16 h = __float2bfloat16(f);
  return *reinterpret_cast<short*>(&h);
}

// ---------------------------------------------------------------------------
// Stage 1: O = relu(X @ W^T + bias) via bf16 MFMA (f32 accumulate).
// Tile 128x64, 4 waves (2x2), per-wave 64x32 = 4x2 frags of 16x16.
// ---------------------------------------------------------------------------
__global__ __launch_bounds__(256) void gemm_mfma_kernel(
    const float* __restrict__ Xa, const float* __restrict__ Wa,
    const float* __restrict__ ba, float* __restrict__ Oa,
    const float* __restrict__ Xb, const float* __restrict__ Wb,
    const float* __restrict__ bb, float* __restrict__ Ob) {
  const float* X = blockIdx.z ? Xb : Xa;
  const float* W = blockIdx.z ? Wb : Wa;
  const float* bias = blockIdx.z ? bb : ba;
  float* O = blockIdx.z ? Ob : Oa;

  __shared__ __align__(16) short As[128 * 40];  // 128 rows x 32 bf16 (+8 pad)
  __shared__ __align__(16) short Ws[64 * 40];

  int t = threadIdx.x;
  int m0 = blockIdx.x * 128, n0 = blockIdx.y * 64;
  int l = t & 63, w = t >> 6;
  int wm = (w >> 1) * 64, wn = (w & 1) * 32;
  int lr = l & 15, ko = (l >> 4) * 8;

  f32x4 acc[4][2];
#pragma unroll
  for (int m = 0; m < 4; ++m)
#pragma unroll
    for (int n = 0; n < 2; ++n) acc[m][n] = f32x4{0.f, 0.f, 0.f, 0.f};

  for (int k0 = 0; k0 < 512; k0 += 32) {
#pragma unroll
    for (int s = 0; s < 4; ++s) {
      int slot = t + s * 256;
      int row = slot >> 3, q = (slot & 7) << 2;
      float4 v = *reinterpret_cast<const float4*>(&X[(m0 + row) * 512 + k0 + q]);
      short4b sv = {f2bf(v.x), f2bf(v.y), f2bf(v.z), f2bf(v.w)};
      *reinterpret_cast<short4b*>(&As[row * 40 + q]) = sv;
    }
#pragma unroll
    for (int s = 0; s < 2; ++s) {
      int slot = t + s * 256;
      int row = slot >> 3, q = (slot & 7) << 2;
      float4 v = *reinterpret_cast<const float4*>(&W[(n0 + row) * 512 + k0 + q]);
      short4b sv = {f2bf(v.x), f2bf(v.y), f2bf(v.z), f2bf(v.w)};
      *reinterpret_cast<short4b*>(&Ws[row * 40 + q]) = sv;
    }
    __syncthreads();

    short8b afr[4], bfr[2];
#pragma unroll
    for (int m = 0; m < 4; ++m)
      afr[m] = *reinterpret_cast<const short8b*>(&As[(wm + m * 16 + lr) * 40 + ko]);
#pragma unroll
    for (int n = 0; n < 2; ++n)
      bfr[n] = *reinterpret_cast<const short8b*>(&Ws[(wn + n * 16 + lr) * 40 + ko]);
#pragma unroll
    for (int m = 0; m < 4; ++m)
#pragma unroll
      for (int n = 0; n < 2; ++n)
        acc[m][n] = __builtin_amdgcn_mfma_f32_16x16x32_bf16(afr[m], bfr[n], acc[m][n], 0, 0, 0);
    __syncthreads();
  }

#pragma unroll
  for (int n = 0; n < 2; ++n) {
    int col = n0 + wn + n * 16 + lr;
    float bv = bias[col];
#pragma unroll
    for (int m = 0; m < 4; ++m) {
      int rbase = m0 + wm + m * 16 + (l >> 4) * 4;
#pragma unroll
      for (int r = 0; r < 4; ++r) {
        float v = acc[m][n][r] + bv;
        O[(rbase + r) * 512 + col] = v > 0.f ? v : 0.f;
      }
    }
  }
}

// ---------------------------------------------------------------------------
// Stage 1.5: per (bh, j) compact the nonzero B entries.
// Pair = (B*2log2e, qm) where qm = -2*q[c] with c packed into the low 6
// mantissa bits (rel perturbation 2^-17 — harmless).  Lists padded to ×4
// with exact-zero pairs.  Also emits Kj = sum_{nz} q_c.
// grid (64*8) blocks; 256 threads = 32 j x 8 scanners; two-pass scan with
// width-8 shfl prefix (no runtime-indexed register arrays -> no scratch).
// ---------------------------------------------------------------------------
__global__ __launch_bounds__(256) void compact_kernel(
    const float* __restrict__ Br, const float* __restrict__ q,
    float2* __restrict__ Cb, unsigned* __restrict__ Cnt, float* __restrict__ Ksum) {
  int blk = blockIdx.x;
  int bh = blk >> 3, jblk = blk & 7;
  int t = threadIdx.x;
  int jl = t >> 3, p = t & 7;
  __shared__ float Bls[32][65];
  __shared__ float qls[64];

  const float* Bbase = Br + bh * 16384 + jblk * 2048;
#pragma unroll
  for (int it = 0; it < 2; ++it) {
    int idx = it * 256 + t;           // 512 float4 slots: 32 rows x 16 quads
    int row = idx >> 4, c4 = (idx & 15) << 2;
    float4 v = *reinterpret_cast<const float4*>(&Bbase[row * 64 + c4]);
    Bls[row][c4 + 0] = v.x; Bls[row][c4 + 1] = v.y;
    Bls[row][c4 + 2] = v.z; Bls[row][c4 + 3] = v.w;
  }
  if (t < 64) qls[t] = q[t];
  __syncthreads();

  int c0 = p * 8;
  // pass 1: count
  int nz = 0;
  float K = 0.f;
#pragma unroll
  for (int cc = 0; cc < 8; ++cc) {
    float v = Bls[jl][c0 + cc];
    if (v > 0.f) { ++nz; K += qls[c0 + cc]; }
  }
  // width-8 inclusive prefix
  int incl = nz;
#pragma unroll
  for (int d = 1; d < 8; d <<= 1) {
    int u = __shfl_up(incl, d, 8);
    if (p >= d) incl += u;
  }
  int off = incl - nz;
  int total = __shfl(incl, 7, 8);

  // pass 2: write
  float2* dst = Cb + (bh * 256 + jblk * 32 + jl) * 64;
  int k = off;
#pragma unroll
  for (int cc = 0; cc < 8; ++cc) {
    int c = c0 + cc;
    float v = Bls[jl][c];
    if (v > 0.f) {
      unsigned qb = (__float_as_uint(-2.f * qls[c]) & ~63u) | (unsigned)c;
      dst[k] = make_float2(v * SC2, __uint_as_float(qb));
      ++k;
    }
  }
  // K reduce over the 8 scanners
#pragma unroll
  for (int d = 1; d < 8; d <<= 1) K += __shfl_xor(K, d, 8);

  if (p == 7) {
    int cnt = total;
    while (cnt & 3) { dst[cnt] = make_float2(0.f, 0.f); ++cnt; }
    Cnt[bh * 256 + jblk * 32 + jl] = (unsigned)cnt;
    Ksum[bh * 256 + jblk * 32 + jl] = K;
  }
}

// ---------------------------------------------------------------------------
// Stage 2 (sparse): M''[i,j] = sum_{s in nz(j)} qm_s * sigma(2 A_ic B_jc)
// computed in rcp-PAIRS:  q0*s0+q1*s1 = (q0*u1+q1*u0)*rcp(u0*u1), u=e+1.
// Pair list is wave-uniform -> scalar loads (no LDS staging).
// grid (64 bh, 8 jblk, 2 isplit); 512 threads; g=t>>7 owns 8 j's, il=t&127.
// A staged [i][c] pad-65 (conflict-free: bank = (il + c) & 31).
// ---------------------------------------------------------------------------
__global__ __launch_bounds__(512, 8) void attmap_kernel(
    const float* __restrict__ Ar, const float2* __restrict__ Cb,
    const unsigned* __restrict__ Cnt,
    float* __restrict__ rowpart, float* __restrict__ colsum) {
  int bh = blockIdx.x, jblk = blockIdx.y, isplit = blockIdx.z;
  int t = threadIdx.x;
  int il = t & 127;
  int g = __builtin_amdgcn_readfirstlane(t >> 7);  // wave-uniform group id
  __shared__ __align__(16) float Als[128 * 65];
  __shared__ float red[512];
  __shared__ float cpart[8][8];

  const float* Abase = Ar + bh * 16384 + isplit * 8192;
#pragma unroll
  for (int it = 0; it < 4; ++it) {
    int idx = it * 512 + t;           // float4 slot: 128 i x 16 quads
    int r = idx >> 4, c4 = (idx & 15) << 2;
    float4 v = *reinterpret_cast<const float4*>(&Abase[r * 64 + c4]);
    Als[r * 65 + c4 + 0] = v.x; Als[r * 65 + c4 + 1] = v.y;
    Als[r * 65 + c4 + 2] = v.z; Als[r * 65 + c4 + 3] = v.w;
  }
  __syncthreads();

  const float* Arow = &Als[il * 65];
  float acc[8];

#pragma unroll
  for (int jj = 0; jj < 8; ++jj) {
    int jl = g * 8 + jj;  // uniform
    int n = (int)__builtin_amdgcn_readfirstlane(Cnt[bh * 256 + jblk * 32 + jl]);
    const float4* P4 = reinterpret_cast<const float4*>(Cb + (bh * 256 + jblk * 32 + jl) * 64);
    float accj = 0.f;
#pragma unroll 1
    for (int s = 0; s < n; s += 4) {
      float4 u = P4[s >> 1];        // (b0,q0,b1,q1) — wave-uniform -> s_load
      float4 v = P4[(s >> 1) + 1];  // (b2,q2,b3,q3)
      float a0 = Arow[__float_as_uint(u.y) & 63u];
      float a1 = Arow[__float_as_uint(u.w) & 63u];
      float a2 = Arow[__float_as_uint(v.y) & 63u];
      float a3 = Arow[__float_as_uint(v.w) & 63u];
      float e0 = fast_exp2(fminf(a0 * u.x, 60.f));
      float e1 = fast_exp2(fminf(a1 * u.z, 60.f));
      float e2 = fast_exp2(fminf(a2 * v.x, 60.f));
      float e3 = fast_exp2(fminf(a3 * v.z, 60.f));
      float u0 = e0 + 1.f, u1 = e1 + 1.f, u2 = e2 + 1.f, u3 = e3 + 1.f;
      float n01 = fmaf(u.w, u0, u.y * u1);
      float n23 = fmaf(v.w, u2, v.y * u3);
      float r01 = fast_rcp(u0 * u1);
      float r23 = fast_rcp(u2 * u3);
      accj = fmaf(n01, r01, accj);
      accj = fmaf(n23, r23, accj);
    }
    acc[jj] = accj;
  }

  float rs = 0.f;
#pragma unroll
  for (int jj = 0; jj < 8; ++jj) rs += acc[jj];
  red[t] = rs;

  int lane = t & 63, w = t >> 6;
#pragma unroll
  for (int jj = 0; jj < 8; ++jj) {
    float v = acc[jj];
#pragma unroll
    for (int off = 32; off >= 1; off >>= 1) v += __shfl_xor(v, off);
    if (lane == 0) cpart[w][jj] = v;
  }
  __syncthreads();
  if (t < 128) {
    rowpart[(bh * 8 + jblk) * 256 + isplit * 128 + t] =
        red[t] + red[t + 128] + red[t + 256] + red[t + 384];
  } else if (t < 160) {
    int jl = t - 128;
    int gg = jl >> 3, jj = jl & 7;
    colsum[(bh * 2 + isplit) * 256 + jblk * 32 + jl] =
        cpart[2 * gg][jj] + cpart[2 * gg + 1][jj];
  }
}

// ---------------------------------------------------------------------------
// Stage 3: per (bh): softmax over 256 row/col means (+Kj shift on cols),
// temps to ws, pooled outputs into out[0:8192].  512 threads.
// ---------------------------------------------------------------------------
__global__ __launch_bounds__(512) void softmax_pool_kernel(
    const float* __restrict__ rowpart, const float* __restrict__ colsum,
    const float* __restrict__ Ksum,
    const float* __restrict__ A0, const float* __restrict__ B0,
    float* __restrict__ b2a, float* __restrict__ a2b, float* __restrict__ out) {
  int bh = blockIdx.x;
  int b = bh >> 3, h = bh & 7;
  int t = threadIdx.x;
  int tt = t & 255;
  int lane = t & 63, w = (t >> 6) & 3;
  __shared__ float redA[4], redB[4], redC[4], redD[4];
  __shared__ float tA[256], tB[256];
  __shared__ float pp[8][64];

  float r = 0.f;
#pragma unroll
  for (int jb = 0; jb < 8; ++jb) r += rowpart[(bh * 8 + jb) * 256 + tt];
  r *= (1.f / 256.f);
  float cs = Ksum[bh * 256 + tt] +
             (colsum[(bh * 2 + 0) * 256 + tt] + colsum[(bh * 2 + 1) * 256 + tt]) * (1.f / 256.f);

  float mr = r, mc = cs;
#pragma unroll
  for (int off = 32; off >= 1; off >>= 1) {
    mr = fmaxf(mr, __shfl_xor(mr, off));
    mc = fmaxf(mc, __shfl_xor(mc, off));
  }
  if (lane == 0) { redA[w] = mr; redB[w] = mc; }
  __syncthreads();
  mr = fmaxf(fmaxf(redA[0], redA[1]), fmaxf(redA[2], redA[3]));
  mc = fmaxf(fmaxf(redB[0], redB[1]), fmaxf(redB[2], redB[3]));

  float er = fast_exp2((r - mr) * LOG2E);
  float ec = fast_exp2((cs - mc) * LOG2E);
  float sr = er, sc = ec;
#pragma unroll
  for (int off = 32; off >= 1; off >>= 1) {
    sr += __shfl_xor(sr, off);
    sc += __shfl_xor(sc, off);
  }
  if (lane == 0) { redC[w] = sr; redD[w] = sc; }
  __syncthreads();
  sr = redC[0] + redC[1] + redC[2] + redC[3];
  sc = redD[0] + redD[1] + redD[2] + redD[3];

  float vb2a = er * fast_rcp(sr);
  float va2b = ec * fast_rcp(sc);
  tA[tt] = vb2a; tB[tt] = va2b;
  b2a[bh * 256 + tt] = vb2a;
  a2b[bh * 256 + tt] = va2b;
  __syncthreads();

  int c = t & 63, iq = t >> 6;  // 8 groups x 32 i
  const float* Ab = A0 + b * 131072 + h * 16384;
  const float* Bb = B0 + b * 131072 + h * 16384;
  float pa = 0.f, pb = 0.f;
#pragma unroll 4
  for (int ii = 0; ii < 32; ++ii) {
    int i = (iq << 5) + ii;
    pa = fmaf(Ab[i * 64 + c], tA[i], pa);
    pb = fmaf(Bb[i * 64 + c], tB[i], pb);
  }
  pp[iq][c] = pa;
  __syncthreads();
  if (t < 64) {
    float s = 0.f;
#pragma unroll
    for (int k = 0; k < 8; ++k) s += pp[k][t];
    out[b * 1024 + h * 64 + t] = s;
  }
  __syncthreads();
  pp[iq][c] = pb;
  __syncthreads();
  if (t < 64) {
    float s = 0.f;
#pragma unroll
    for (int k = 0; k < 8; ++k) s += pp[k][t];
    out[b * 1024 + 512 + h * 64 + t] = s;
  }
}

// ---------------------------------------------------------------------------
// Stage 4: out1[b,i] = mean_h temp_b2a ; out2[b,j] = mean_h temp_a2b
// ---------------------------------------------------------------------------
__global__ __launch_bounds__(256) void mean_heads_kernel(
    const float* __restrict__ b2a, const float* __restrict__ a2b,
    float* __restrict__ out) {
  int b = blockIdx.x, t = threadIdx.x;
  float s1 = 0.f, s2 = 0.f;
#pragma unroll
  for (int h = 0; h < 8; ++h) {
    s1 += b2a[(b * 8 + h) * 256 + t];
    s2 += a2b[(b * 8 + h) * 256 + t];
  }
  out[8192 + b * 256 + t] = s1 * 0.125f;
  out[10240 + b * 256 + t] = s2 * 0.125f;
}

extern "C" void kernel_launch(void* const* d_in, const int* in_sizes, int n_in,
                              void* d_out, int out_size, void* d_ws, size_t ws_size,
                              hipStream_t stream) {
  const float* A  = (const float*)d_in[0];
  const float* B  = (const float*)d_in[1];
  const float* W1 = (const float*)d_in[2];
  const float* b1 = (const float*)d_in[3];
  const float* W2 = (const float*)d_in[4];
  const float* b2 = (const float*)d_in[5];
  const float* q  = (const float*)d_in[6];
  float* out = (float*)d_out;
  float* ws = (float*)d_ws;

  float*    Ar      = ws;                          // 1,048,576 f
  float*    Brr     = ws + 1048576;                // 1,048,576 f
  float2*   Cb      = (float2*)(ws + 2097152);     // 1,048,576 f2 (8 MB)
  unsigned* Cnt     = (unsigned*)(ws + 4194304);   // 16,384 u32
  float*    Ksum    = ws + 4210688;                // 16,384 f
  float*    rowpart = ws + 4227072;                // 131,072 f
  float*    colsum  = ws + 4358144;                // 32,768 f  (end ~17.6 MB)
  float*    b2a     = ws;                          // alias Ar (dead after attmap)
  float*    a2b     = ws + 16384;

  gemm_mfma_kernel<<<dim3(16, 8, 2), 256, 0, stream>>>(A, W1, b1, Ar, B, W2, b2, Brr);
  compact_kernel<<<512, 256, 0, stream>>>(Brr, q, Cb, Cnt, Ksum);
  attmap_kernel<<<dim3(64, 8, 2), 512, 0, stream>>>(Ar, Cb, Cnt, rowpart, colsum);
  softmax_pool_kernel<<<64, 512, 0, stream>>>(rowpart, colsum, Ksum, A, B, b2a, a2b, out);
  mean_heads_kernel<<<8, 256, 0, stream>>>(b2a, a2b, out);
}